// Round 1
// baseline (270.636 us; speedup 1.0000x reference)
//
#include <hip/hip_runtime.h>
#include <hip/hip_bf16.h>
#include <math.h>

// Problem: B=32, T=1024, C=256, HS=64. fp32 in/out.
// out = softmax_causal( (x@Wq^T) @ (x@Wk^T)^T / 8 ) @ (x@Wv^T)
//
// Round-0 structure (correctness-first fp32 baseline):
//   proj_kernel: tiled GEMM -> k,q,v in d_ws (3 * 8 MB = 24 MB scratch)
//   attn_kernel: flash-style, 1 block = (batch, 64-query tile), online softmax
// LDS pitches chosen so inner-loop reads are <=2-way bank conflicts (free per
// m136); P-tile scatter write is 8-way (known, ~7% of tile cost, fix later).

#define B_  32
#define T_  1024
#define C_  256
#define HS_ 64

// ---------------- projection: {k,q,v} = x @ W^T ----------------
// grid = 512 row-tiles * 3 weights, block = 256 (16x16 threads, 4x4 reg tile)
__global__ __launch_bounds__(256) void proj_kernel(
    const float* __restrict__ x,
    const float* __restrict__ Wk,
    const float* __restrict__ Wq,
    const float* __restrict__ Wv,
    float* __restrict__ kb, float* __restrict__ qb, float* __restrict__ vb)
{
    const int w  = blockIdx.x % 3;
    const int mt = blockIdx.x / 3;
    const int m0 = mt * 64;
    const float* __restrict__ W  = (w == 0) ? Wk : (w == 1) ? Wq : Wv;
    float*       __restrict__ ob = (w == 0) ? kb : (w == 1) ? qb : vb;

    __shared__ float As[64][33];   // x rows, pitch 33: stride 132%32=4 -> <=2-way
    __shared__ float Bs[64][33];   // W rows

    const int tid = threadIdx.x;
    const int tm = tid >> 4, tn = tid & 15;
    const int i0 = tm * 4, j0 = tn * 4;

    float acc[4][4] = {};

    for (int c0 = 0; c0 < C_; c0 += 32) {
        __syncthreads();
        #pragma unroll
        for (int it = 0; it < 2; ++it) {
            int f   = tid + it * 256;     // float4 id 0..511
            int row = f >> 3;             // 0..63
            int col = (f & 7) << 2;       // 0..28
            float4 a = *(const float4*)&x[(size_t)(m0 + row) * C_ + c0 + col];
            As[row][col + 0] = a.x; As[row][col + 1] = a.y;
            As[row][col + 2] = a.z; As[row][col + 3] = a.w;
            float4 b = *(const float4*)&W[(size_t)row * C_ + c0 + col];
            Bs[row][col + 0] = b.x; Bs[row][col + 1] = b.y;
            Bs[row][col + 2] = b.z; Bs[row][col + 3] = b.w;
        }
        __syncthreads();
        #pragma unroll
        for (int kk = 0; kk < 32; ++kk) {
            float a[4], b[4];
            #pragma unroll
            for (int r = 0; r < 4; ++r) a[r] = As[i0 + r][kk];
            #pragma unroll
            for (int c = 0; c < 4; ++c) b[c] = Bs[j0 + c][kk];
            #pragma unroll
            for (int r = 0; r < 4; ++r)
                #pragma unroll
                for (int c = 0; c < 4; ++c)
                    acc[r][c] = fmaf(a[r], b[c], acc[r][c]);
        }
    }

    #pragma unroll
    for (int r = 0; r < 4; ++r) {
        float4 o4 = { acc[r][0], acc[r][1], acc[r][2], acc[r][3] };
        *(float4*)&ob[(size_t)(m0 + i0 + r) * HS_ + j0] = o4;
    }
}

// ---------------- attention: flash-style, online softmax ----------------
// grid = 32 batches * 16 q-tiles (heavy tiles dispatched first), block = 256
__global__ __launch_bounds__(256) void attn_kernel(
    const float* __restrict__ qb, const float* __restrict__ kb,
    const float* __restrict__ vb, float* __restrict__ out)
{
    const int batch = blockIdx.x & 31;
    const int qt    = 15 - (blockIdx.x >> 5);   // heavy (long) tiles first
    const int q0    = qt * 64;

    __shared__ float Qs[64][65];   // pitch 65: row stride 65%32=1, 4-row stride 260%32=4
    __shared__ float Ks[64][65];
    __shared__ float Vs[64][65];
    __shared__ float Ps[64][65];

    const int tid = threadIdx.x;
    const int tm = tid >> 4, tn = tid & 15;
    const int i0 = tm * 4, j0 = tn * 4;

    // load + pre-scale Q tile (fold 1/sqrt(64) into Q)
    {
        const int row = tid >> 4;
        const int c4  = (tid & 15) << 2;
        #pragma unroll
        for (int it = 0; it < 4; ++it) {
            int rr = row + it * 16;
            float4 v4 = *(const float4*)&qb[((size_t)batch * T_ + q0 + rr) * HS_ + c4];
            Qs[rr][c4 + 0] = v4.x * 0.125f; Qs[rr][c4 + 1] = v4.y * 0.125f;
            Qs[rr][c4 + 2] = v4.z * 0.125f; Qs[rr][c4 + 3] = v4.w * 0.125f;
        }
    }

    float o[4][4] = {};
    float m_r[4] = { -INFINITY, -INFINITY, -INFINITY, -INFINITY };
    float l_r[4] = {};

    for (int st = 0; st <= qt; ++st) {
        const int s0 = st * 64;
        __syncthreads();   // previous PV done before K/V overwrite
        {
            const int row = tid >> 4;
            const int c4  = (tid & 15) << 2;
            #pragma unroll
            for (int it = 0; it < 4; ++it) {
                int rr = row + it * 16;
                float4 k4 = *(const float4*)&kb[((size_t)batch * T_ + s0 + rr) * HS_ + c4];
                Ks[rr][c4 + 0] = k4.x; Ks[rr][c4 + 1] = k4.y;
                Ks[rr][c4 + 2] = k4.z; Ks[rr][c4 + 3] = k4.w;
                float4 v4 = *(const float4*)&vb[((size_t)batch * T_ + s0 + rr) * HS_ + c4];
                Vs[rr][c4 + 0] = v4.x; Vs[rr][c4 + 1] = v4.y;
                Vs[rr][c4 + 2] = v4.z; Vs[rr][c4 + 3] = v4.w;
            }
        }
        __syncthreads();

        // S = (Q*0.125) @ K^T, 4x4 per thread
        float s[4][4] = {};
        #pragma unroll
        for (int kk = 0; kk < 64; ++kk) {
            float a[4], b[4];
            #pragma unroll
            for (int r = 0; r < 4; ++r) a[r] = Qs[i0 + r][kk];
            #pragma unroll
            for (int c = 0; c < 4; ++c) b[c] = Ks[j0 + c][kk];
            #pragma unroll
            for (int r = 0; r < 4; ++r)
                #pragma unroll
                for (int c = 0; c < 4; ++c)
                    s[r][c] = fmaf(a[r], b[c], s[r][c]);
        }

        if (st == qt) {   // causal mask on diagonal tile (local j > local i)
            #pragma unroll
            for (int r = 0; r < 4; ++r)
                #pragma unroll
                for (int c = 0; c < 4; ++c)
                    if (j0 + c > i0 + r) s[r][c] = -INFINITY;
        }

        // online softmax per row; row spread over 16 consecutive lanes (same tm)
        #pragma unroll
        for (int r = 0; r < 4; ++r) {
            float mloc = fmaxf(fmaxf(s[r][0], s[r][1]), fmaxf(s[r][2], s[r][3]));
            #pragma unroll
            for (int d = 1; d < 16; d <<= 1) mloc = fmaxf(mloc, __shfl_xor(mloc, d));
            float mn = fmaxf(m_r[r], mloc);
            float al = __expf(m_r[r] - mn);   // first tile: exp(-inf)=0
            float p[4], rs = 0.f;
            #pragma unroll
            for (int c = 0; c < 4; ++c) { p[c] = __expf(s[r][c] - mn); rs += p[c]; }
            #pragma unroll
            for (int d = 1; d < 16; d <<= 1) rs += __shfl_xor(rs, d);
            m_r[r] = mn;
            l_r[r] = l_r[r] * al + rs;
            #pragma unroll
            for (int c = 0; c < 4; ++c) o[r][c] *= al;
            Ps[i0 + r][j0 + 0] = p[0]; Ps[i0 + r][j0 + 1] = p[1];
            Ps[i0 + r][j0 + 2] = p[2]; Ps[i0 + r][j0 + 3] = p[3];
        }
        __syncthreads();

        // O += P @ V  (thread's tn re-used as h-tile)
        #pragma unroll 8
        for (int j = 0; j < 64; ++j) {
            float pa[4];
            #pragma unroll
            for (int r = 0; r < 4; ++r) pa[r] = Ps[i0 + r][j];
            float v0 = Vs[j][j0 + 0], v1 = Vs[j][j0 + 1];
            float v2 = Vs[j][j0 + 2], v3 = Vs[j][j0 + 3];
            #pragma unroll
            for (int r = 0; r < 4; ++r) {
                o[r][0] = fmaf(pa[r], v0, o[r][0]);
                o[r][1] = fmaf(pa[r], v1, o[r][1]);
                o[r][2] = fmaf(pa[r], v2, o[r][2]);
                o[r][3] = fmaf(pa[r], v3, o[r][3]);
            }
        }
    }

    #pragma unroll
    for (int r = 0; r < 4; ++r) {
        float invl = 1.0f / l_r[r];
        float4 res = { o[r][0] * invl, o[r][1] * invl, o[r][2] * invl, o[r][3] * invl };
        *(float4*)&out[((size_t)batch * T_ + q0 + i0 + r) * HS_ + j0] = res;
    }
}

extern "C" void kernel_launch(void* const* d_in, const int* in_sizes, int n_in,
                              void* d_out, int out_size, void* d_ws, size_t ws_size,
                              hipStream_t stream) {
    (void)in_sizes; (void)n_in; (void)out_size; (void)ws_size;
    const float* x  = (const float*)d_in[0];
    const float* Wk = (const float*)d_in[1];
    const float* Wq = (const float*)d_in[2];
    const float* Wv = (const float*)d_in[3];
    float* outp = (float*)d_out;

    float* ws = (float*)d_ws;                 // need 24 MB scratch
    const size_t SZ = (size_t)B_ * T_ * HS_;  // 2M floats per buffer
    float* kb = ws;
    float* qb = ws + SZ;
    float* vb = ws + 2 * SZ;

    hipLaunchKernelGGL(proj_kernel, dim3(512 * 3), dim3(256), 0, stream,
                       x, Wk, Wq, Wv, kb, qb, vb);
    hipLaunchKernelGGL(attn_kernel, dim3(512), dim3(256), 0, stream,
                       qb, kb, vb, outp);
}

// Round 2
// 123.360 us; speedup vs baseline: 2.1939x; 2.1939x over previous
//
#include <hip/hip_runtime.h>
#include <hip/hip_bf16.h>
#include <math.h>

// B=32, T=1024, C=256, HS=64. fp32 in/out, bf16 MFMA internally.
// proj: fusedqk[m][0:64]=k, [64:128]=q*0.125*log2e (bf16); vt[b][h][s]=v (bf16, pre-transposed)
// attn: 1 wave/block, 32 queries; S^T = K @ Q^T; no-max base-2 online softmax
//       (|s'| << 127 so exp2 can't overflow; softmax is shift-invariant anyway);
//       P^T -> LDS (packed b64) -> PV as O^T = V^T @ P^T. No barriers.

#define B_  32
#define T_  1024
#define C_  256
#define HS_ 64
#define QSCALE 0.1803368801111204f   // 0.125 * log2(e)

typedef __attribute__((ext_vector_type(8))) short bf16x8;
typedef __attribute__((ext_vector_type(4))) float f32x4;

static __device__ __forceinline__ unsigned short f2bf(float f) {
    unsigned u = __builtin_bit_cast(unsigned, f);
    u += 0x7FFFu + ((u >> 16) & 1u);               // RNE
    return (unsigned short)(u >> 16);
}

static __device__ __forceinline__ float fexp2(float x) {
#if __has_builtin(__builtin_amdgcn_exp2f)
    return __builtin_amdgcn_exp2f(x);
#else
    return exp2f(x);
#endif
}

// ---------------- projection GEMM (bf16 MFMA) ----------------
// grid 512 (64 rows each), block 256 = 4 waves; wave w covers n-range 48w..48w+47
// D = out^T (A = W rows, B = x^T): lane col = m, rows = n (4 consecutive per reg)
__global__ __launch_bounds__(256) void proj_kernel(
    const float* __restrict__ x, const float* __restrict__ Wk,
    const float* __restrict__ Wq, const float* __restrict__ Wv,
    unsigned short* __restrict__ fqk, unsigned short* __restrict__ vt)
{
    __shared__ unsigned short xs[64][40];    // pitch 40: 16B-aligned rows, 2-way max
    __shared__ unsigned short ws[192][40];
    const int tid = threadIdx.x;
    const int lane = tid & 63, w = tid >> 6;
    const int q4 = lane >> 4, l15 = lane & 15;
    const int m0 = blockIdx.x * 64;

    f32x4 acc[3][4];
    #pragma unroll
    for (int a = 0; a < 3; ++a)
        #pragma unroll
        for (int b = 0; b < 4; ++b) acc[a][b] = (f32x4)0.0f;

    for (int c0 = 0; c0 < C_; c0 += 32) {
        __syncthreads();
        #pragma unroll
        for (int it = 0; it < 2; ++it) {               // xs: 64x32
            int qq = tid + it * 256;
            int row = qq >> 3, col = (qq & 7) << 2;
            float4 v = *(const float4*)&x[(size_t)(m0 + row) * C_ + c0 + col];
            unsigned lo = f2bf(v.x) | ((unsigned)f2bf(v.y) << 16);
            unsigned hi = f2bf(v.z) | ((unsigned)f2bf(v.w) << 16);
            *(uint2*)&xs[row][col] = make_uint2(lo, hi);
        }
        #pragma unroll
        for (int it = 0; it < 6; ++it) {               // ws: 192x32 (k|q|v rows)
            int qq = tid + it * 256;
            int row = qq >> 3, col = (qq & 7) << 2;
            const float* src = (row < 64) ? &Wk[(size_t)row * C_]
                             : (row < 128) ? &Wq[(size_t)(row - 64) * C_]
                             : &Wv[(size_t)(row - 128) * C_];
            float sc = (row >= 64 && row < 128) ? QSCALE : 1.0f;
            float4 v = *(const float4*)&src[c0 + col];
            unsigned lo = f2bf(v.x * sc) | ((unsigned)f2bf(v.y * sc) << 16);
            unsigned hi = f2bf(v.z * sc) | ((unsigned)f2bf(v.w * sc) << 16);
            *(uint2*)&ws[row][col] = make_uint2(lo, hi);
        }
        __syncthreads();
        bf16x8 a[3], b[4];
        #pragma unroll
        for (int nt = 0; nt < 3; ++nt) a[nt] = *(const bf16x8*)&ws[48 * w + nt * 16 + l15][q4 * 8];
        #pragma unroll
        for (int mt = 0; mt < 4; ++mt) b[mt] = *(const bf16x8*)&xs[mt * 16 + l15][q4 * 8];
        #pragma unroll
        for (int nt = 0; nt < 3; ++nt)
            #pragma unroll
            for (int mt = 0; mt < 4; ++mt)
                acc[nt][mt] = __builtin_amdgcn_mfma_f32_16x16x32_bf16(a[nt], b[mt], acc[nt][mt], 0, 0, 0);
    }

    #pragma unroll
    for (int nt = 0; nt < 3; ++nt) {
        const int nb = 48 * w + nt * 16 + q4 * 4;      // 4 consecutive n per reg
        #pragma unroll
        for (int mt = 0; mt < 4; ++mt) {
            const int m = m0 + mt * 16 + l15;
            f32x4 v = acc[nt][mt];
            if (nb < 128) {                            // k | q -> fused row-major
                unsigned lo = f2bf(v.x) | ((unsigned)f2bf(v.y) << 16);
                unsigned hi = f2bf(v.z) | ((unsigned)f2bf(v.w) << 16);
                *(uint2*)&fqk[(size_t)m * 128 + nb] = make_uint2(lo, hi);
            } else {                                   // v -> transposed vt[b][h][s]
                const int batch = m >> 10, s = m & 1023;
                #pragma unroll
                for (int r = 0; r < 4; ++r) {
                    float vv = (r == 0) ? v.x : (r == 1) ? v.y : (r == 2) ? v.z : v.w;
                    vt[((size_t)batch * 64 + (nb - 128 + r)) * 1024 + s] = f2bf(vv);
                }
            }
        }
    }
}

// ---------------- attention (flash, no-max, base-2) ----------------
// grid 1024 = 32 batches x 32 q-tiles(32), heavy-first; block = 1 wave (64)
__global__ __launch_bounds__(64) void attn_kernel(
    const unsigned short* __restrict__ fqk,
    const unsigned short* __restrict__ vt,
    float* __restrict__ out)
{
    const int lane = threadIdx.x;
    const int q4 = lane >> 4, l15 = lane & 15;
    const int batch = blockIdx.x & 31;
    const int qt = 31 - (blockIdx.x >> 5);
    const int q0 = qt * 32;
    const int ns = (qt >> 1) + 1;

    __shared__ unsigned short Ps[32][72];   // P row-major [i][s], pitch 72

    // Q B-frags (fixed for the block): n=i, k=h
    bf16x8 qf[2][2];
    #pragma unroll
    for (int it = 0; it < 2; ++it)
        #pragma unroll
        for (int kc = 0; kc < 2; ++kc)
            qf[it][kc] = *(const bf16x8*)&fqk[(size_t)(batch * T_ + q0 + it * 16 + l15) * 128 + 64 + kc * 32 + q4 * 8];

    f32x4 o[4][2];
    #pragma unroll
    for (int ht = 0; ht < 4; ++ht)
        #pragma unroll
        for (int it = 0; it < 2; ++it) o[ht][it] = (f32x4)0.0f;
    float l[2] = {0.f, 0.f};

    const unsigned short* kbase = &fqk[(size_t)(batch * T_) * 128];
    const unsigned short* vbase = &vt[(size_t)batch * 64 * 1024];

    bf16x8 ak[4][2];                        // K A-frags, prefetched
    #pragma unroll
    for (int st16 = 0; st16 < 4; ++st16)
        #pragma unroll
        for (int kc = 0; kc < 2; ++kc)
            ak[st16][kc] = *(const bf16x8*)&kbase[(size_t)(st16 * 16 + l15) * 128 + kc * 32 + q4 * 8];

    for (int st = 0; st < ns; ++st) {
        const int s0 = st * 64;
        // S^T = K @ Q^T : lane col = query i, rows = s
        f32x4 s[4][2];
        #pragma unroll
        for (int st16 = 0; st16 < 4; ++st16)
            #pragma unroll
            for (int it = 0; it < 2; ++it) {
                f32x4 c = (f32x4)0.0f;
                c = __builtin_amdgcn_mfma_f32_16x16x32_bf16(ak[st16][0], qf[it][0], c, 0, 0, 0);
                c = __builtin_amdgcn_mfma_f32_16x16x32_bf16(ak[st16][1], qf[it][1], c, 0, 0, 0);
                s[st16][it] = c;
            }
        // V^T A-frags for this tile (independent of softmax -> overlaps)
        bf16x8 av[4][2];
        #pragma unroll
        for (int ht = 0; ht < 4; ++ht)
            #pragma unroll
            for (int kc = 0; kc < 2; ++kc)
                av[ht][kc] = *(const bf16x8*)&vbase[(size_t)(ht * 16 + l15) * 1024 + s0 + kc * 32 + q4 * 8];
        // prefetch next K tile
        if (st + 1 < ns) {
            #pragma unroll
            for (int st16 = 0; st16 < 4; ++st16)
                #pragma unroll
                for (int kc = 0; kc < 2; ++kc)
                    ak[st16][kc] = *(const bf16x8*)&kbase[(size_t)(s0 + 64 + st16 * 16 + l15) * 128 + kc * 32 + q4 * 8];
        }
        // p = 2^(s'), accumulate l, write P^T transposed (4 consecutive s -> b64)
        const bool last = (st == ns - 1);
        #pragma unroll
        for (int st16 = 0; st16 < 4; ++st16) {
            #pragma unroll
            for (int it = 0; it < 2; ++it) {
                const int iloc = it * 16 + l15;
                float p[4];
                #pragma unroll
                for (int r = 0; r < 4; ++r) {
                    float pv = fexp2(s[st16][it][r]);
                    if (last) {
                        int sl = st16 * 16 + q4 * 4 + r;
                        if (s0 + sl > q0 + iloc) pv = 0.0f;   // causal mask
                    }
                    p[r] = pv;
                    l[it] += pv;
                }
                unsigned lo = f2bf(p[0]) | ((unsigned)f2bf(p[1]) << 16);
                unsigned hi = f2bf(p[2]) | ((unsigned)f2bf(p[3]) << 16);
                *(uint2*)&Ps[iloc][st16 * 16 + q4 * 4] = make_uint2(lo, hi);
            }
        }
        // PV: O^T += V^T @ P^T (single wave: lgkmcnt ordering, no barrier)
        #pragma unroll
        for (int it = 0; it < 2; ++it) {
            bf16x8 bp0 = *(const bf16x8*)&Ps[it * 16 + l15][q4 * 8];
            bf16x8 bp1 = *(const bf16x8*)&Ps[it * 16 + l15][32 + q4 * 8];
            #pragma unroll
            for (int ht = 0; ht < 4; ++ht) {
                o[ht][it] = __builtin_amdgcn_mfma_f32_16x16x32_bf16(av[ht][0], bp0, o[ht][it], 0, 0, 0);
                o[ht][it] = __builtin_amdgcn_mfma_f32_16x16x32_bf16(av[ht][1], bp1, o[ht][it], 0, 0, 0);
            }
        }
    }

    // epilogue: full l = reduce over quads (disjoint s per quad), then scale+store
    #pragma unroll
    for (int it = 0; it < 2; ++it) {
        float lf = l[it];
        lf += __shfl_xor(lf, 16);
        lf += __shfl_xor(lf, 32);
        l[it] = 1.0f / lf;
    }
    #pragma unroll
    for (int ht = 0; ht < 4; ++ht)
        #pragma unroll
        for (int it = 0; it < 2; ++it) {
            f32x4 v = o[ht][it];
            float4 res = make_float4(v.x * l[it], v.y * l[it], v.z * l[it], v.w * l[it]);
            *(float4*)&out[(size_t)(batch * T_ + q0 + it * 16 + l15) * HS_ + ht * 16 + q4 * 4] = res;
        }
}

extern "C" void kernel_launch(void* const* d_in, const int* in_sizes, int n_in,
                              void* d_out, int out_size, void* d_ws, size_t ws_size,
                              hipStream_t stream) {
    (void)in_sizes; (void)n_in; (void)out_size; (void)ws_size;
    const float* x  = (const float*)d_in[0];
    const float* Wk = (const float*)d_in[1];
    const float* Wq = (const float*)d_in[2];
    const float* Wv = (const float*)d_in[3];

    unsigned short* fqk = (unsigned short*)d_ws;                          // 8 MB
    unsigned short* vtb = (unsigned short*)((char*)d_ws + (size_t)32768 * 128 * 2); // 4 MB

    hipLaunchKernelGGL(proj_kernel, dim3(512), dim3(256), 0, stream,
                       x, Wk, Wq, Wv, fqk, vtb);
    hipLaunchKernelGGL(attn_kernel, dim3(1024), dim3(64), 0, stream,
                       fqk, vtb, (float*)d_out);
}

// Round 3
// 121.568 us; speedup vs baseline: 2.2262x; 1.0147x over previous
//
#include <hip/hip_runtime.h>
#include <hip/hip_bf16.h>
#include <math.h>

// B=32, T=1024, C=256, HS=64. fp32 in/out, bf16 MFMA internally.
// prep: W -> bf16 wbf[192][256] (k|q*qscale|v rows), once.
// proj: barrier-free, LDS-free GEMM. wave = 32m x 96n; W A-frags direct from
//       L1/L2 (bf16), x converted in-reg (v_perm pack). Outputs:
//       fqk[m][0:64]=k, [64:128]=q*0.125*log2e ; vt[b][h][s]=v (transposed).
// attn: 4 waves/block on one 32-query tile; s-tiles strided across waves
//       (no-max base-2 flash => combine is a pure sum of o and l partials).
//       P^T through per-wave LDS, PV as O^T = V^T @ P^T. 2 barriers/block.

#define B_  32
#define T_  1024
#define C_  256
#define HS_ 64
#define QSCALE 0.1803368801111204f   // 0.125 * log2(e)

typedef __attribute__((ext_vector_type(8))) short bf16x8;
typedef __attribute__((ext_vector_type(4))) float f32x4;

static __device__ __forceinline__ unsigned short f2bf(float f) {
    unsigned u = __builtin_bit_cast(unsigned, f);
    u += 0x7FFFu + ((u >> 16) & 1u);               // RNE
    return (unsigned short)(u >> 16);
}
// pack two floats to packed bf16 pair (round-half-up; 2 adds + 1 v_perm)
static __device__ __forceinline__ unsigned pack_bf2(float a, float b) {
    unsigned ua = __builtin_bit_cast(unsigned, a) + 0x8000u;
    unsigned ub = __builtin_bit_cast(unsigned, b) + 0x8000u;
    return __builtin_amdgcn_perm(ub, ua, 0x07060302u);  // [ua.hi16, ub.hi16]
}
static __device__ __forceinline__ float fexp2(float x) {
#if __has_builtin(__builtin_amdgcn_exp2f)
    return __builtin_amdgcn_exp2f(x);
#else
    return exp2f(x);
#endif
}

// ---------------- prep: W -> bf16 (q rows pre-scaled) ----------------
__global__ __launch_bounds__(256) void prep_kernel(
    const float* __restrict__ Wk, const float* __restrict__ Wq,
    const float* __restrict__ Wv, unsigned short* __restrict__ wbf)
{
    const int idx = blockIdx.x * 256 + threadIdx.x;   // 0..12287 float4s
    const int row = idx >> 6, c4 = (idx & 63) << 2;
    const float* src; float sc = 1.0f;
    if (row < 64)       src = &Wk[(size_t)row * C_];
    else if (row < 128) { src = &Wq[(size_t)(row - 64) * C_]; sc = QSCALE; }
    else                src = &Wv[(size_t)(row - 128) * C_];
    float4 v = *(const float4*)&src[c4];
    uint2 o = make_uint2(pack_bf2(v.x * sc, v.y * sc), pack_bf2(v.z * sc, v.w * sc));
    *(uint2*)&wbf[(size_t)row * C_ + c4] = o;
}

// ---------------- proj: barrier-free bf16 MFMA GEMM ----------------
// grid 512 (64 m-rows each), block 256 = 4 waves; wave w: wm=w&1 (32 m), wn=w>>1 (96 n)
__global__ __launch_bounds__(256) void proj_kernel(
    const float* __restrict__ x, const unsigned short* __restrict__ wbf,
    unsigned short* __restrict__ fqk, unsigned short* __restrict__ vt)
{
    const int tid = threadIdx.x;
    const int lane = tid & 63, w = tid >> 6;
    const int wm = w & 1, wn = w >> 1;
    const int q4 = lane >> 4, l15 = lane & 15;
    const int mbase = blockIdx.x * 64 + wm * 32;

    f32x4 acc[6][2];
    #pragma unroll
    for (int nt = 0; nt < 6; ++nt)
        #pragma unroll
        for (int mt = 0; mt < 2; ++mt) acc[nt][mt] = (f32x4)0.0f;

    for (int c0 = 0; c0 < C_; c0 += 32) {
        bf16x8 bx[2];
        #pragma unroll
        for (int mt = 0; mt < 2; ++mt) {
            const float* px = &x[(size_t)(mbase + mt * 16 + l15) * C_ + c0 + q4 * 8];
            float4 v0 = *(const float4*)px;
            float4 v1 = *(const float4*)(px + 4);
            union { bf16x8 v; unsigned u[4]; } t;
            t.u[0] = pack_bf2(v0.x, v0.y); t.u[1] = pack_bf2(v0.z, v0.w);
            t.u[2] = pack_bf2(v1.x, v1.y); t.u[3] = pack_bf2(v1.z, v1.w);
            bx[mt] = t.v;
        }
        #pragma unroll
        for (int nt = 0; nt < 6; ++nt) {
            bf16x8 a = *(const bf16x8*)&wbf[(size_t)(wn * 96 + nt * 16 + l15) * C_ + c0 + q4 * 8];
            #pragma unroll
            for (int mt = 0; mt < 2; ++mt)
                acc[nt][mt] = __builtin_amdgcn_mfma_f32_16x16x32_bf16(a, bx[mt], acc[nt][mt], 0, 0, 0);
        }
    }

    #pragma unroll
    for (int nt = 0; nt < 6; ++nt) {
        const int nbase = wn * 96 + nt * 16 + q4 * 4;
        #pragma unroll
        for (int mt = 0; mt < 2; ++mt) {
            const int m = mbase + mt * 16 + l15;
            f32x4 v = acc[nt][mt];
            if (nbase < 128) {       // k | q -> fused row-major [m][128]
                uint2 o = make_uint2(pack_bf2(v.x, v.y), pack_bf2(v.z, v.w));
                *(uint2*)&fqk[(size_t)m * 128 + nbase] = o;
            } else {                 // v -> transposed vt[b][h][s]
                const int batch = m >> 10, s = m & 1023, h = nbase - 128;
                vt[((size_t)batch * 64 + h + 0) * 1024 + s] = f2bf(v.x);
                vt[((size_t)batch * 64 + h + 1) * 1024 + s] = f2bf(v.y);
                vt[((size_t)batch * 64 + h + 2) * 1024 + s] = f2bf(v.z);
                vt[((size_t)batch * 64 + h + 3) * 1024 + s] = f2bf(v.w);
            }
        }
    }
}

// ---------------- attention: 4-wave split-s flash, no-max, base-2 ----------------
// grid 1024 = 32 batches x 32 q-tiles (heavy-first); block 256 = 4 waves
__global__ __launch_bounds__(256) void attn_kernel(
    const unsigned short* __restrict__ fqk,
    const unsigned short* __restrict__ vt,
    float* __restrict__ out)
{
    __shared__ __align__(16) char smem[34816];   // Ps[4][32][72] (18.4K) U ocomb(32K)+lcomb(2K)

    const int tid = threadIdx.x;
    const int lane = tid & 63, w = tid >> 6;
    const int q4 = lane >> 4, l15 = lane & 15;
    const int batch = blockIdx.x & 31;
    const int qt = 31 - (blockIdx.x >> 5);
    const int q0 = qt * 32;
    const int ns = (qt >> 1) + 1;

    unsigned short (*Ps)[72] = (unsigned short(*)[72])(smem + w * 4608);

    // Q B-frags (shared by all 4 waves; L1-hot)
    bf16x8 qf[2][2];
    #pragma unroll
    for (int it = 0; it < 2; ++it)
        #pragma unroll
        for (int kc = 0; kc < 2; ++kc)
            qf[it][kc] = *(const bf16x8*)&fqk[(size_t)(batch * T_ + q0 + it * 16 + l15) * 128 + 64 + kc * 32 + q4 * 8];

    f32x4 o[4][2];
    #pragma unroll
    for (int ht = 0; ht < 4; ++ht)
        #pragma unroll
        for (int it = 0; it < 2; ++it) o[ht][it] = (f32x4)0.0f;
    float l[2] = {0.f, 0.f};

    const unsigned short* kbase = &fqk[(size_t)(batch * T_) * 128];
    const unsigned short* vbase = &vt[(size_t)batch * 64 * 1024];

    for (int st = w; st < ns; st += 4) {
        const int s0 = st * 64;
        const bool last = (st == ns - 1);
        #pragma unroll
        for (int hf = 0; hf < 2; ++hf) {
            const int sh = s0 + hf * 32;
            // K A-frags for this 32-s half
            bf16x8 ak[2][2];
            #pragma unroll
            for (int st16 = 0; st16 < 2; ++st16)
                #pragma unroll
                for (int kc = 0; kc < 2; ++kc)
                    ak[st16][kc] = *(const bf16x8*)&kbase[(size_t)(sh + st16 * 16 + l15) * 128 + kc * 32 + q4 * 8];
            // V^T A-frags for this half
            bf16x8 av[4];
            #pragma unroll
            for (int ht = 0; ht < 4; ++ht)
                av[ht] = *(const bf16x8*)&vbase[(size_t)(ht * 16 + l15) * 1024 + sh + q4 * 8];
            // S^T = K @ Q^T
            f32x4 s[2][2];
            #pragma unroll
            for (int st16 = 0; st16 < 2; ++st16)
                #pragma unroll
                for (int it = 0; it < 2; ++it) {
                    f32x4 c = (f32x4)0.0f;
                    c = __builtin_amdgcn_mfma_f32_16x16x32_bf16(ak[st16][0], qf[it][0], c, 0, 0, 0);
                    c = __builtin_amdgcn_mfma_f32_16x16x32_bf16(ak[st16][1], qf[it][1], c, 0, 0, 0);
                    s[st16][it] = c;
                }
            // p = 2^s', accumulate l, write P^T (packed b64)
            #pragma unroll
            for (int st16 = 0; st16 < 2; ++st16)
                #pragma unroll
                for (int it = 0; it < 2; ++it) {
                    const int iloc = it * 16 + l15;
                    float p[4];
                    #pragma unroll
                    for (int r = 0; r < 4; ++r) {
                        float pv = fexp2(s[st16][it][r]);
                        if (last) {
                            int sl = sh + st16 * 16 + q4 * 4 + r;
                            if (sl > q0 + iloc) pv = 0.0f;   // causal
                        }
                        p[r] = pv;
                        l[it] += pv;
                    }
                    uint2 pw = make_uint2(pack_bf2(p[0], p[1]), pack_bf2(p[2], p[3]));
                    *(uint2*)&Ps[iloc][hf * 32 + st16 * 16 + q4 * 4] = pw;
                }
            // PV: O^T += V^T @ P^T (single-wave LDS round trip, no barrier)
            #pragma unroll
            for (int it = 0; it < 2; ++it) {
                bf16x8 bp = *(const bf16x8*)&Ps[it * 16 + l15][hf * 32 + q4 * 8];
                #pragma unroll
                for (int ht = 0; ht < 4; ++ht)
                    o[ht][it] = __builtin_amdgcn_mfma_f32_16x16x32_bf16(av[ht], bp, o[ht][it], 0, 0, 0);
            }
        }
    }

    // wave-internal l reduce over quads (disjoint s per quad)
    #pragma unroll
    for (int it = 0; it < 2; ++it) {
        l[it] += __shfl_xor(l[it], 16);
        l[it] += __shfl_xor(l[it], 32);
    }

    __syncthreads();   // all waves done with Ps before combine-buffer reuse
    float4* ocomb = (float4*)smem;                 // [w][ht][it][lane]
    float*  lcomb = (float*)(smem + 32768);        // [w][it][lane]
    #pragma unroll
    for (int ht = 0; ht < 4; ++ht)
        #pragma unroll
        for (int it = 0; it < 2; ++it) {
            f32x4 v = o[ht][it];
            ocomb[((w * 4 + ht) * 2 + it) * 64 + lane] = make_float4(v.x, v.y, v.z, v.w);
        }
    #pragma unroll
    for (int it = 0; it < 2; ++it) lcomb[(w * 2 + it) * 64 + lane] = l[it];
    __syncthreads();

    // wave w reduces head-tile ht = w and stores
    #pragma unroll
    for (int it = 0; it < 2; ++it) {
        float4 a = make_float4(0.f, 0.f, 0.f, 0.f);
        float lt = 0.f;
        #pragma unroll
        for (int src = 0; src < 4; ++src) {
            float4 t = ocomb[((src * 4 + w) * 2 + it) * 64 + lane];
            a.x += t.x; a.y += t.y; a.z += t.z; a.w += t.w;
            lt += lcomb[(src * 2 + it) * 64 + lane];
        }
        float inv = 1.0f / lt;
        float4 res = make_float4(a.x * inv, a.y * inv, a.z * inv, a.w * inv);
        *(float4*)&out[(size_t)(batch * T_ + q0 + it * 16 + l15) * HS_ + w * 16 + q4 * 4] = res;
    }
}

extern "C" void kernel_launch(void* const* d_in, const int* in_sizes, int n_in,
                              void* d_out, int out_size, void* d_ws, size_t ws_size,
                              hipStream_t stream) {
    (void)in_sizes; (void)n_in; (void)out_size; (void)ws_size;
    const float* x  = (const float*)d_in[0];
    const float* Wk = (const float*)d_in[1];
    const float* Wq = (const float*)d_in[2];
    const float* Wv = (const float*)d_in[3];

    unsigned short* wbf = (unsigned short*)d_ws;                                   // 96 KB
    unsigned short* fqk = (unsigned short*)((char*)d_ws + 98304);                  // 8 MB
    unsigned short* vtb = (unsigned short*)((char*)d_ws + 98304 + (size_t)32768 * 128 * 2); // 4 MB

    hipLaunchKernelGGL(prep_kernel, dim3(48),   dim3(256), 0, stream, Wk, Wq, Wv, wbf);
    hipLaunchKernelGGL(proj_kernel, dim3(512),  dim3(256), 0, stream, x, wbf, fqk, vtb);
    hipLaunchKernelGGL(attn_kernel, dim3(1024), dim3(256), 0, stream, fqk, vtb, (float*)d_out);
}